// Round 3
// baseline (1200.188 us; speedup 1.0000x reference)
//
#include <hip/hip_runtime.h>
#include <hip/hip_bf16.h>

#define NN 100000
#define NE 1250000
#define DD 64
#define RR 16
#define NTILE 6250        // NN/16 dst-tiles
#define NBINS 100000      // (dst>>4)*16 + rel
#define NBLK_SCAN 391     // ceil(NBINS/256)
#define CAPROWS 224       // staged x-rows per tile (mean 200, sd 14 -> ~4% tiles overflow a few rows, global fallback)
#define DLCAP 576         // staged dst-local bytes (P(cnt>576)~0, global fallback kept)
#define DNSTRIDE 65       // Dn row stride floats: bank = (node + och) % 32 -> ~2-way on scatter

typedef __attribute__((ext_vector_type(8))) short s16x8;
typedef __attribute__((ext_vector_type(4))) float f32x4;

static __device__ __forceinline__ unsigned short f2bf(float v) {
    __hip_bfloat16 h = __float2bfloat16(v);
    return __builtin_bit_cast(unsigned short, h);
}
static __device__ __forceinline__ unsigned int pack2(float a, float b) {
    return ((unsigned int)f2bf(b) << 16) | (unsigned int)f2bf(a);
}
static __device__ __forceinline__ void lds_addf(float* p, float v) {
    __hip_atomic_fetch_add(p, v, __ATOMIC_RELAXED, __HIP_MEMORY_SCOPE_WORKGROUP);
}

// ---------------- sort edges by (dst-tile, rel): counting sort, 100k bins ----------------

__global__ void hist_key(const int* __restrict__ dst, const int* __restrict__ et,
                         int* __restrict__ cnt) {
    int e = blockIdx.x * 256 + threadIdx.x;
    if (e < NE) atomicAdd(&cnt[(dst[e] >> 4) * 16 + et[e]], 1);
}

__global__ __launch_bounds__(256) void scan1(const int* __restrict__ cnt,
                                             int* __restrict__ rp, int* __restrict__ part) {
    __shared__ int s[256];
    int i = blockIdx.x * 256 + threadIdx.x;
    int v = (i < NBINS) ? cnt[i] : 0;
    s[threadIdx.x] = v;
    __syncthreads();
    for (int off = 1; off < 256; off <<= 1) {
        int t = (threadIdx.x >= off) ? s[threadIdx.x - off] : 0;
        __syncthreads();
        s[threadIdx.x] += t;
        __syncthreads();
    }
    if (i < NBINS) rp[i] = s[threadIdx.x] - v;        // exclusive
    if (threadIdx.x == 255) part[blockIdx.x] = s[255];
}

__global__ void scan2(int* __restrict__ part, int* __restrict__ rp) {
    __shared__ int s[NBLK_SCAN];
    if (threadIdx.x < NBLK_SCAN) s[threadIdx.x] = part[threadIdx.x];
    __syncthreads();
    if (threadIdx.x == 0) {
        int acc = 0;
        for (int b = 0; b < NBLK_SCAN; ++b) { int t = s[b]; s[b] = acc; acc += t; }
        rp[NBINS] = NE;
    }
    __syncthreads();
    if (threadIdx.x < NBLK_SCAN) part[threadIdx.x] = s[threadIdx.x];
}

__global__ void scan3(int* __restrict__ rp, const int* __restrict__ part, int* __restrict__ cur) {
    int i = blockIdx.x * 256 + threadIdx.x;
    if (i < NBINS) {
        int v = rp[i] + part[blockIdx.x];
        rp[i] = v;
        cur[i] = v;
    }
}

// ep[p] = src | (dst&15)<<20
__global__ void scatter_key(const int* __restrict__ src, const int* __restrict__ dst,
                            const int* __restrict__ et, int* __restrict__ cur,
                            unsigned int* __restrict__ ep) {
    int e = blockIdx.x * 256 + threadIdx.x;
    if (e >= NE) return;
    int d = dst[e];
    int p = atomicAdd(&cur[(d >> 4) * 16 + et[e]], 1);
    ep[p] = (unsigned int)src[e] | ((unsigned int)(d & 15) << 20);
}

// ---------------- precision prep ----------------

// wt[l][p][o][d] = bf16( (p<16 ? W_l[p] : sw_l)[d][o] )
__global__ void prep_w2(const float* __restrict__ W1, const float* __restrict__ sw1,
                        const float* __restrict__ W2, const float* __restrict__ sw2,
                        unsigned short* __restrict__ wt) {
    int i = blockIdx.x * 256 + threadIdx.x;
    if (i >= 2 * 17 * DD * DD) return;
    int d = i & 63;
    int o = (i >> 6) & 63;
    int p = (i >> 12) % 17;
    int l = i / (17 * DD * DD);
    const float* srcp;
    if (p < 16) srcp = (l ? W2 : W1) + p * DD * DD;
    else        srcp = (l ? sw2 : sw1);
    wt[i] = f2bf(srcp[d * DD + o]);
}

__global__ void prep_x2(const float* __restrict__ x, unsigned short* __restrict__ xb) {
    int i = blockIdx.x * blockDim.x + threadIdx.x;
    if (i < NN * DD) xb[i] = f2bf(x[i]);
}

// ---------------- fused layer (v3: atomic-scatter, no indicator MFMA) ----------------
// Block = 16-dst tile, 512 threads / 8 waves = (plane-half eh) x (och-quarter oq).
// Swapped-operand MFMA: cA = mfma(Wfrag, xfrag) -> lane (c,q) holds msg[edge b0+c][och oq*16+q*4+v]
// for v=0..3. Scatter = 4 x ds_add_f32 into fp32 Dn[node*65 + och] (stride 65 -> ~2-way banks).
// No indicator build, no bf16 message re-pack, no cross-chunk accumulator chain: chunks are
// fully independent -> pipelineable. rp bounds live in registers via __shfl (zero-memory path).
__global__ __launch_bounds__(512, 6) void fused_layer(
    const unsigned short* __restrict__ xb,   // [N][64] bf16 layer input
    const unsigned short* __restrict__ wt,   // [17][64][64] bf16 (o-major, d inner)
    const int* __restrict__ rp,              // [NBINS+1]
    const unsigned int* __restrict__ ep,     // [E] src | dstloc<<20
    const float* __restrict__ bias,
    const float* __restrict__ xres,          // fp32 residual or nullptr
    unsigned short* __restrict__ outb,       // bf16 out (layer 1) or nullptr
    float* __restrict__ outf)                // fp32 out (layer 2) or nullptr
{
    __shared__ __attribute__((aligned(16))) unsigned char Ash[CAPROWS * 128]; // 28672 B
    __shared__ __attribute__((aligned(8)))  unsigned char dlb[DLCAP + 32];    //   608 B
    __shared__ __attribute__((aligned(16))) float Dn[16 * DNSTRIDE + 16];     //  4224 B

    const int tid  = threadIdx.x;
    const int w    = tid >> 6;
    const int lane = tid & 63;
    const int c = lane & 15;
    const int q = lane >> 4;
    const int eh = w >> 2;        // plane half: 0 -> r 0..7, 1 -> r 8..15 + self
    const int oq = w & 3;         // och quarter
    const int tile = blockIdx.x;
    const int n0 = tile * 16;

    // rp bounds into registers (lane-indexed), accessed via shuffle — no memory on bounds path
    int rpv = 0;
    if (lane < 17) rpv = rp[tile * 16 + lane];
    const int e0  = __shfl(rpv, 0, 64);
    const int cnt = __shfl(rpv, 16, 64) - e0;

    // ---- zero Dn ----
    for (int i = tid; i < 16 * DNSTRIDE + 16; i += 512) Dn[i] = 0.f;

    // ---- stage dst-local bytes ----
    {
        const int lim = cnt < DLCAP ? cnt : DLCAP;
        for (int i = tid; i < lim; i += 512)
            dlb[i] = (unsigned char)(ep[e0 + i] >> 20);
    }
    // ---- stage x rows (2 threads/row, 4 independent 16B loads each), XOR-swizzled slots ----
    {
        const int nrows = cnt < CAPROWS ? cnt : CAPROWS;
        const int half = tid & 1;
        for (int i = tid >> 1; i < nrows; i += 256) {
            int src = (int)(ep[e0 + i] & 0xFFFFF);
            const unsigned short* xr = xb + (size_t)src * DD + half * 32;
            s16x8 v0 = *(const s16x8*)(xr);
            s16x8 v1 = *(const s16x8*)(xr + 8);
            s16x8 v2 = *(const s16x8*)(xr + 16);
            s16x8 v3 = *(const s16x8*)(xr + 24);
            unsigned char* bp = Ash + i * 128;
            const int h8 = (i & 7);
            *(s16x8*)(bp + (((half * 4 + 0) ^ h8) * 16)) = v0;
            *(s16x8*)(bp + (((half * 4 + 1) ^ h8) * 16)) = v1;
            *(s16x8*)(bp + (((half * 4 + 2) ^ h8) * 16)) = v2;
            *(s16x8*)(bp + (((half * 4 + 3) ^ h8) * 16)) = v3;
        }
    }
    __syncthreads();

    const bool dlOK = (cnt <= DLCAP);
    // A-operand (weights): A[m=c][k=q*8+j] = wt[plane][och=oq*16+c][d]
    const unsigned short* wb = wt + (size_t)(oq * 16 + c) * DD + q * 8;
    const int ochBase = oq * 16 + q * 4;    // +v for this lane's 4 outputs
    const int rbeg = eh * 8;

    s16x8 w0 = *(const s16x8*)(wb + (size_t)rbeg * (DD * DD));
    s16x8 w1 = *(const s16x8*)(wb + (size_t)rbeg * (DD * DD) + 32);

    for (int r = rbeg; r < rbeg + 8; ++r) {
        // prefetch next plane (eh=1, r=15 prefetches the self plane 16; eh=0 last prefetch unused)
        const unsigned short* nwp = wb + (size_t)(r + 1) * (DD * DD);
        s16x8 nw0 = *(const s16x8*)(nwp);
        s16x8 nw1 = *(const s16x8*)(nwp + 32);

        const int s0 = __shfl(rpv, r, 64);
        const int s1 = __shfl(rpv, r + 1, 64);
        for (int b0 = s0; b0 < s1; b0 += 16) {
            const bool valid = (b0 + c < s1);
            const int rA = (valid ? b0 + c : s1 - 1) - e0;

            int node;
            if (dlOK) node = dlb[rA];
            else      node = (int)(ep[e0 + rA] >> 20);

            s16x8 a0, a1;
            if (rA < CAPROWS) {
                const unsigned char* ap = Ash + rA * 128;
                const int off = (q ^ (rA & 7)) * 16;
                a0 = *(const s16x8*)(ap + off);
                a1 = *(const s16x8*)(ap + (off ^ 64));
            } else {
                int src = (int)(ep[e0 + rA] & 0xFFFFF);
                const unsigned short* xr = xb + (size_t)src * DD + q * 8;
                a0 = *(const s16x8*)(xr);
                a1 = *(const s16x8*)(xr + 32);
            }

            f32x4 acc = {0.f, 0.f, 0.f, 0.f};
            acc = __builtin_amdgcn_mfma_f32_16x16x32_bf16(w0, a0, acc, 0, 0, 0);
            acc = __builtin_amdgcn_mfma_f32_16x16x32_bf16(w1, a1, acc, 0, 0, 0);

            if (valid) {
                float* dp = Dn + node * DNSTRIDE + ochBase;
                lds_addf(dp + 0, acc[0]);
                lds_addf(dp + 1, acc[1]);
                lds_addf(dp + 2, acc[2]);
                lds_addf(dp + 3, acc[3]);
            }
        }
        w0 = nw0; w1 = nw1;
    }

    // ---- self plane (eh==1 waves; w0,w1 now hold plane 16) ----
    if (eh) {
        const unsigned short* xr = xb + (size_t)(n0 + c) * DD + q * 8;
        s16x8 a0 = *(const s16x8*)(xr);
        s16x8 a1 = *(const s16x8*)(xr + 32);
        f32x4 acc = {0.f, 0.f, 0.f, 0.f};
        acc = __builtin_amdgcn_mfma_f32_16x16x32_bf16(w0, a0, acc, 0, 0, 0);
        acc = __builtin_amdgcn_mfma_f32_16x16x32_bf16(w1, a1, acc, 0, 0, 0);
        float* dp = Dn + c * DNSTRIDE + ochBase;
        lds_addf(dp + 0, acc[0]);
        lds_addf(dp + 1, acc[1]);
        lds_addf(dp + 2, acc[2]);
        lds_addf(dp + 3, acc[3]);
    }
    __syncthreads();

    // ---- epilogue: thread t -> output idx {2t, 2t+1}: node = idx>>6, och = idx&63 ----
    {
        const int idx  = tid * 2;
        const int node = idx >> 6;
        const int och  = idx & 63;
        float v0 = Dn[node * DNSTRIDE + och]     + bias[och];
        float v1 = Dn[node * DNSTRIDE + och + 1] + bias[och + 1];
        if (xres) {
            const float2 rv = *(const float2*)(xres + (size_t)(n0 + node) * DD + och);
            v0 += rv.x; v1 += rv.y;
        }
        v0 = fmaxf(v0, 0.f);
        v1 = fmaxf(v1, 0.f);
        if (outb)
            *(unsigned int*)(outb + (size_t)(n0 + node) * DD + och) = pack2(v0, v1);
        if (outf) {
            float2 o = {v0, v1};
            *(float2*)(outf + (size_t)(n0 + node) * DD + och) = o;
        }
    }
}

// ================= launch =================

extern "C" void kernel_launch(void* const* d_in, const int* in_sizes, int n_in,
                              void* d_out, int out_size, void* d_ws, size_t ws_size,
                              hipStream_t stream)
{
    (void)in_sizes; (void)n_in; (void)out_size; (void)ws_size;
    const float* x    = (const float*)d_in[0];
    const int*   ei   = (const int*)d_in[1];
    const int*   et   = (const int*)d_in[2];
    const float* W1   = (const float*)d_in[3];
    const float* sw1  = (const float*)d_in[4];
    const float* b1   = (const float*)d_in[5];
    const float* W2   = (const float*)d_in[6];
    const float* sw2  = (const float*)d_in[7];
    const float* b2   = (const float*)d_in[8];
    float* out = (float*)d_out;

    const int* srcA = ei;
    const int* dstA = ei + NE;

    char* ws = (char*)d_ws;
    unsigned short* xb   = (unsigned short*)(ws);                 // 12,800,000
    unsigned short* h1b  = (unsigned short*)(ws + 12800000);      // 12,800,000
    unsigned short* wt2  = (unsigned short*)(ws + 25600000);      //    278,528
    unsigned int*   ep   = (unsigned int*)(ws + 25878528);        //  5,000,000
    int*            rp   = (int*)(ws + 30878528);                 //    400,004
    int*            cnt  = (int*)(ws + 31278544);                 //    400,000
    int*            cur  = (int*)(ws + 31678544);                 //    400,000
    int*            part = (int*)(ws + 32078544);                 //      1,600

    const int NB_E    = (NE + 255) / 256;        // 4883
    const int NB_ELEM = (NN * DD + 255) / 256;   // 25000
    const int WPL = 17 * DD * DD;                // wt2 per-layer stride

    // sort edges by (dst-tile, rel) — once, reused by both layers
    hipMemsetAsync(cnt, 0, NBINS * sizeof(int), stream);
    hist_key<<<NB_E, 256, 0, stream>>>(dstA, et, cnt);
    scan1<<<NBLK_SCAN, 256, 0, stream>>>(cnt, rp, part);
    scan2<<<1, 512, 0, stream>>>(part, rp);
    scan3<<<NBLK_SCAN, 256, 0, stream>>>(rp, part, cur);
    scatter_key<<<NB_E, 256, 0, stream>>>(srcA, dstA, et, cur, ep);

    // precision prep
    prep_w2<<<(2 * 17 * DD * DD + 255) / 256, 256, 0, stream>>>(W1, sw1, W2, sw2, wt2);
    prep_x2<<<NB_ELEM, 256, 0, stream>>>(x, xb);

    // ---- layer 1 (residual) ----
    fused_layer<<<NTILE, 512, 0, stream>>>(xb, wt2, rp, ep, b1, x, h1b, nullptr);
    // ---- layer 2 (no residual) ----
    fused_layer<<<NTILE, 512, 0, stream>>>(h1b, wt2 + WPL, rp, ep, b2, nullptr, nullptr, out);
}

// Round 4
// 527.174 us; speedup vs baseline: 2.2766x; 2.2766x over previous
//
#include <hip/hip_runtime.h>
#include <hip/hip_bf16.h>

#define NN 100000
#define NE 1250000
#define DD 64
#define RR 16
#define NTILE 6250        // NN/16 dst-tiles
#define NBINS 100000      // (dst>>4)*16 + rel
#define NBLK_SCAN 391     // ceil(NBINS/256)
#define CAPROWS 224       // staged x-rows per tile (mean 200, sd 14 -> ~4% tiles overflow a few rows, global fallback)
#define DLCAP 576         // staged dst-local bytes (P(cnt>576)~0, shuffle fallback kept)

typedef __attribute__((ext_vector_type(8))) short s16x8;
typedef __attribute__((ext_vector_type(4))) float f32x4;

static __device__ __forceinline__ unsigned short f2bf(float v) {
    __hip_bfloat16 h = __float2bfloat16(v);
    return __builtin_bit_cast(unsigned short, h);
}
static __device__ __forceinline__ unsigned int pack2(float a, float b) {
    return ((unsigned int)f2bf(b) << 16) | (unsigned int)f2bf(a);
}

// ---------------- sort edges by (dst-tile, rel): counting sort, 100k bins ----------------

__global__ void hist_key(const int* __restrict__ dst, const int* __restrict__ et,
                         int* __restrict__ cnt) {
    int e = blockIdx.x * 256 + threadIdx.x;
    if (e < NE) atomicAdd(&cnt[(dst[e] >> 4) * 16 + et[e]], 1);
}

__global__ __launch_bounds__(256) void scan1(const int* __restrict__ cnt,
                                             int* __restrict__ rp, int* __restrict__ part) {
    __shared__ int s[256];
    int i = blockIdx.x * 256 + threadIdx.x;
    int v = (i < NBINS) ? cnt[i] : 0;
    s[threadIdx.x] = v;
    __syncthreads();
    for (int off = 1; off < 256; off <<= 1) {
        int t = (threadIdx.x >= off) ? s[threadIdx.x - off] : 0;
        __syncthreads();
        s[threadIdx.x] += t;
        __syncthreads();
    }
    if (i < NBINS) rp[i] = s[threadIdx.x] - v;        // exclusive
    if (threadIdx.x == 255) part[blockIdx.x] = s[255];
}

__global__ void scan2(int* __restrict__ part, int* __restrict__ rp) {
    __shared__ int s[NBLK_SCAN];
    if (threadIdx.x < NBLK_SCAN) s[threadIdx.x] = part[threadIdx.x];
    __syncthreads();
    if (threadIdx.x == 0) {
        int acc = 0;
        for (int b = 0; b < NBLK_SCAN; ++b) { int t = s[b]; s[b] = acc; acc += t; }
        rp[NBINS] = NE;
    }
    __syncthreads();
    if (threadIdx.x < NBLK_SCAN) part[threadIdx.x] = s[threadIdx.x];
}

__global__ void scan3(int* __restrict__ rp, const int* __restrict__ part, int* __restrict__ cur) {
    int i = blockIdx.x * 256 + threadIdx.x;
    if (i < NBINS) {
        int v = rp[i] + part[blockIdx.x];
        rp[i] = v;
        cur[i] = v;
    }
}

// ep[p] = src | (dst&15)<<20
__global__ void scatter_key(const int* __restrict__ src, const int* __restrict__ dst,
                            const int* __restrict__ et, int* __restrict__ cur,
                            unsigned int* __restrict__ ep) {
    int e = blockIdx.x * 256 + threadIdx.x;
    if (e >= NE) return;
    int d = dst[e];
    int p = atomicAdd(&cur[(d >> 4) * 16 + et[e]], 1);
    ep[p] = (unsigned int)src[e] | ((unsigned int)(d & 15) << 20);
}

// ---------------- precision prep ----------------

// wt[l][p][o][d] = bf16( (p<16 ? W_l[p] : sw_l)[d][o] )
__global__ void prep_w2(const float* __restrict__ W1, const float* __restrict__ sw1,
                        const float* __restrict__ W2, const float* __restrict__ sw2,
                        unsigned short* __restrict__ wt) {
    int i = blockIdx.x * 256 + threadIdx.x;
    if (i >= 2 * 17 * DD * DD) return;
    int d = i & 63;
    int o = (i >> 6) & 63;
    int p = (i >> 12) % 17;
    int l = i / (17 * DD * DD);
    const float* srcp;
    if (p < 16) srcp = (l ? W2 : W1) + p * DD * DD;
    else        srcp = (l ? sw2 : sw1);
    wt[i] = f2bf(srcp[d * DD + o]);
}

__global__ void prep_x2(const float* __restrict__ x, unsigned short* __restrict__ xb) {
    int i = blockIdx.x * blockDim.x + threadIdx.x;
    if (i < NN * DD) xb[i] = f2bf(x[i]);
}

// ---------------- fused layer (v4: round-2 structure, serial chains removed) ----------------
// Block = 16-dst tile, 256 threads / 4 waves; wave wid owns och-block wid*16..+15 and walks
// all 17 planes (no cross-wave reduction, one barrier). Fixes vs round-2:
//  - rp bounds live in REGISTERS via one load + __shfl (round-2 loaded rp from global per
//    plane: ~200-400cy unhideable latency x16 on the critical path -> the 13k cy/block wall)
//  - accumulator split D0(even planes)/D1(odd planes): halves the MFMA recurrence
//  - weight prefetch 1 plane ahead maintained across the 2x-unrolled plane loop
//  - 16-edge chunks only (dropped hasB superchunks): -16 VGPR, -half indicator VALU;
//    MFMA issue is 6% busy so the ~5% extra MFMA on >16-edge bins is free
__global__ __launch_bounds__(256, 4) void fused_layer(
    const unsigned short* __restrict__ xb,   // [N][64] bf16 layer input
    const unsigned short* __restrict__ wt,   // [17][64][64] bf16 (o-major, d inner)
    const int* __restrict__ rp,              // [NBINS+1]
    const unsigned int* __restrict__ ep,     // [E] src | dstloc<<20
    const float* __restrict__ bias,
    const float* __restrict__ xres,          // fp32 residual or nullptr
    unsigned short* __restrict__ outb,       // bf16 out (layer 1) or nullptr
    float* __restrict__ outf)                // fp32 out (layer 2) or nullptr
{
    __shared__ __attribute__((aligned(16))) unsigned char Ash[CAPROWS * 128]; // 28672 B
    __shared__ __attribute__((aligned(8)))  unsigned char dlb[DLCAP + 32];    //   608 B

    const int tid  = threadIdx.x;
    const int wid  = tid >> 6;
    const int lane = tid & 63;
    const int c = lane & 15;
    const int q = lane >> 4;
    const int tile = blockIdx.x;
    const int n0 = tile * 16;

    // rp bounds into registers (lane-indexed), accessed via shuffle — no memory on bounds path
    int rpv = 0;
    if (lane < 17) rpv = rp[tile * 16 + lane];
    const int e0  = __shfl(rpv, 0, 64);
    const int cnt = __shfl(rpv, 16, 64) - e0;

    // ---- stage dst-local bytes ----
    {
        const int lim = cnt < DLCAP ? cnt : DLCAP;
        for (int i = tid; i < lim; i += 256)
            dlb[i] = (unsigned char)(ep[e0 + i] >> 20);
        if (tid < 32) {
            int p = lim + tid;
            if (p < DLCAP + 32) dlb[p] = 0xFF;   // pad: never matches c (c<16)
        }
    }
    // ---- stage x rows (2 threads/row, 4 independent 16B loads each), XOR-swizzled slots ----
    {
        const int nrows = cnt < CAPROWS ? cnt : CAPROWS;
        const int half = tid & 1;
        for (int i = tid >> 1; i < nrows; i += 128) {
            int src = (int)(ep[e0 + i] & 0xFFFFF);
            const unsigned short* xr = xb + (size_t)src * DD + half * 32;
            s16x8 v0 = *(const s16x8*)(xr);
            s16x8 v1 = *(const s16x8*)(xr + 8);
            s16x8 v2 = *(const s16x8*)(xr + 16);
            s16x8 v3 = *(const s16x8*)(xr + 24);
            unsigned char* bp = Ash + i * 128;
            const int h8 = (i & 7);
            *(s16x8*)(bp + (((half * 4 + 0) ^ h8) * 16)) = v0;
            *(s16x8*)(bp + (((half * 4 + 1) ^ h8) * 16)) = v1;
            *(s16x8*)(bp + (((half * 4 + 2) ^ h8) * 16)) = v2;
            *(s16x8*)(bp + (((half * 4 + 3) ^ h8) * 16)) = v3;
        }
    }
    __syncthreads();

    const bool dlOK = (cnt <= DLCAP);
    const int och = wid * 16 + c;
    const unsigned short* wbase = wt + (size_t)och * DD + q * 8;
    const short one = (short)0x3F80;

    // one plane's worth of chunks: 16-edge chunks, indicator from dlb, frags from Ash
    auto plane_body = [&](int r, s16x8 W0, s16x8 W1, f32x4& Dst) {
        const int s0 = __shfl(rpv, r, 64);
        const int s1 = __shfl(rpv, r + 1, 64);
        for (int b0 = s0; b0 < s1; b0 += 16) {
            const int rem = s1 - b0;
            const int lbase = b0 - e0;

            // ---- indicator A2 (slots j<4 = edges b0+q*4+j; slots 4..7 = 0) ----
            unsigned da;
            if (dlOK) {
                const unsigned* dl32 = (const unsigned*)dlb;
                int idx = lbase + q * 4;
                int w = idx >> 2;
                int sh = (idx & 3) * 8;
                unsigned long long pa =
                    ((unsigned long long)dl32[w + 1] << 32) | dl32[w];
                da = (unsigned)(pa >> sh);
            } else {
                // huge-tile fallback (cnt > DLCAP, ~never)
                int eA = min(b0 + c, s1 - 1);
                unsigned wa = ep[eA];
                int dl = (b0 + c < s1) ? (int)(wa >> 20) : 31;
                unsigned x0 = (unsigned)__shfl(dl, q * 4 + 0, 64) & 255u;
                unsigned x1 = (unsigned)__shfl(dl, q * 4 + 1, 64) & 255u;
                unsigned x2 = (unsigned)__shfl(dl, q * 4 + 2, 64) & 255u;
                unsigned x3 = (unsigned)__shfl(dl, q * 4 + 3, 64) & 255u;
                da = x0 | (x1 << 8) | (x2 << 16) | (x3 << 24);
            }
            s16x8 a2;
            #pragma unroll
            for (int j = 0; j < 4; ++j) {
                int jj = q * 4 + j;
                a2[j] = ((int)((da >> (8 * j)) & 255) == c && jj < rem) ? one : (short)0;
                a2[j + 4] = 0;
            }

            // ---- A fragment: edge b0+c row, XOR-swizzled LDS (global fallback >= CAPROWS) ----
            int rA = min(b0 + c, s1 - 1) - e0;
            s16x8 a0, a1;
            if (rA < CAPROWS) {
                const unsigned char* ap = Ash + rA * 128;
                const int off = (q ^ (rA & 7)) * 16;
                a0 = *(const s16x8*)(ap + off);
                a1 = *(const s16x8*)(ap + (off ^ 64));
            } else {
                int src = (int)(ep[e0 + rA] & 0xFFFFF);
                const unsigned short* xr = xb + (size_t)src * DD + q * 8;
                a0 = *(const s16x8*)(xr);
                a1 = *(const s16x8*)(xr + 32);
            }

            __builtin_amdgcn_s_setprio(1);
            f32x4 cA = {0.f, 0.f, 0.f, 0.f};
            cA = __builtin_amdgcn_mfma_f32_16x16x32_bf16(a0, W0, cA, 0, 0, 0);
            cA = __builtin_amdgcn_mfma_f32_16x16x32_bf16(a1, W1, cA, 0, 0, 0);
            s16x8 bv;
            #pragma unroll
            for (int j = 0; j < 4; ++j) {
                bv[j]     = (short)f2bf(cA[j]);
                bv[j + 4] = 0;
            }
            Dst = __builtin_amdgcn_mfma_f32_16x16x32_bf16(a2, bv, Dst, 0, 0, 0);
            __builtin_amdgcn_s_setprio(0);
        }
    };

    // plane loop, 2x unrolled: even planes -> D0, odd -> D1; 1-plane-ahead weight prefetch
    s16x8 wc0 = *(const s16x8*)(wbase);
    s16x8 wc1 = *(const s16x8*)(wbase + 32);
    f32x4 D0 = {0.f, 0.f, 0.f, 0.f};
    f32x4 D1 = {0.f, 0.f, 0.f, 0.f};

    for (int rr = 0; rr < 8; ++rr) {
        const int r = rr * 2;
        const unsigned short* p1 = wbase + (size_t)(r + 1) * (DD * DD);
        s16x8 wn0 = *(const s16x8*)(p1);
        s16x8 wn1 = *(const s16x8*)(p1 + 32);
        plane_body(r, wc0, wc1, D0);
        const int r2 = (r + 2 <= 16) ? r + 2 : 16;
        const unsigned short* p2 = wbase + (size_t)r2 * (DD * DD);
        s16x8 t0 = *(const s16x8*)(p2);
        s16x8 t1 = *(const s16x8*)(p2 + 32);
        plane_body(r + 1, wn0, wn1, D1);
        wc0 = t0; wc1 = t1;
    }

    // ---- self plane (wc holds plane 16): one K-half into each accumulator ----
    {
        const unsigned short* xr = xb + (size_t)(n0 + c) * DD + q * 8;
        s16x8 a0 = *(const s16x8*)(xr);
        s16x8 a1 = *(const s16x8*)(xr + 32);
        D0 = __builtin_amdgcn_mfma_f32_16x16x32_bf16(a0, wc0, D0, 0, 0, 0);
        D1 = __builtin_amdgcn_mfma_f32_16x16x32_bf16(a1, wc1, D1, 0, 0, 0);
    }
    f32x4 Dacc = D0 + D1;

    // ---- epilogue: lane (c,q) of wave wid holds node q*4+v, channel wid*16+c ----
    const float bc = bias[och];
    #pragma unroll
    for (int v = 0; v < 4; ++v) {
        const int node = n0 + q * 4 + v;
        float val = Dacc[v] + bc;
        if (xres) val += xres[(size_t)node * DD + och];
        val = fmaxf(val, 0.f);
        if (outf) outf[(size_t)node * DD + och] = val;
        if (outb) {
            float nb = __shfl_xor(val, 1, 64);
            if (!(c & 1))
                *(unsigned int*)(outb + (size_t)node * DD + och) = pack2(val, nb);
        }
    }
}

// ================= launch =================

extern "C" void kernel_launch(void* const* d_in, const int* in_sizes, int n_in,
                              void* d_out, int out_size, void* d_ws, size_t ws_size,
                              hipStream_t stream)
{
    (void)in_sizes; (void)n_in; (void)out_size; (void)ws_size;
    const float* x    = (const float*)d_in[0];
    const int*   ei   = (const int*)d_in[1];
    const int*   et   = (const int*)d_in[2];
    const float* W1   = (const float*)d_in[3];
    const float* sw1  = (const float*)d_in[4];
    const float* b1   = (const float*)d_in[5];
    const float* W2   = (const float*)d_in[6];
    const float* sw2  = (const float*)d_in[7];
    const float* b2   = (const float*)d_in[8];
    float* out = (float*)d_out;

    const int* srcA = ei;
    const int* dstA = ei + NE;

    char* ws = (char*)d_ws;
    unsigned short* xb   = (unsigned short*)(ws);                 // 12,800,000
    unsigned short* h1b  = (unsigned short*)(ws + 12800000);      // 12,800,000
    unsigned short* wt2  = (unsigned short*)(ws + 25600000);      //    278,528
    unsigned int*   ep   = (unsigned int*)(ws + 25878528);        //  5,000,000
    int*            rp   = (int*)(ws + 30878528);                 //    400,004
    int*            cnt  = (int*)(ws + 31278544);                 //    400,000
    int*            cur  = (int*)(ws + 31678544);                 //    400,000
    int*            part = (int*)(ws + 32078544);                 //      1,600

    const int NB_E    = (NE + 255) / 256;        // 4883
    const int NB_ELEM = (NN * DD + 255) / 256;   // 25000
    const int WPL = 17 * DD * DD;                // wt2 per-layer stride

    // sort edges by (dst-tile, rel) — once, reused by both layers
    hipMemsetAsync(cnt, 0, NBINS * sizeof(int), stream);
    hist_key<<<NB_E, 256, 0, stream>>>(dstA, et, cnt);
    scan1<<<NBLK_SCAN, 256, 0, stream>>>(cnt, rp, part);
    scan2<<<1, 512, 0, stream>>>(part, rp);
    scan3<<<NBLK_SCAN, 256, 0, stream>>>(rp, part, cur);
    scatter_key<<<NB_E, 256, 0, stream>>>(srcA, dstA, et, cur, ep);

    // precision prep
    prep_w2<<<(2 * 17 * DD * DD + 255) / 256, 256, 0, stream>>>(W1, sw1, W2, sw2, wt2);
    prep_x2<<<NB_ELEM, 256, 0, stream>>>(x, xb);

    // ---- layer 1 (residual) ----
    fused_layer<<<NTILE, 256, 0, stream>>>(xb, wt2, rp, ep, b1, x, h1b, nullptr);
    // ---- layer 2 (no residual) ----
    fused_layer<<<NTILE, 256, 0, stream>>>(h1b, wt2 + WPL, rp, ep, b2, nullptr, nullptr, out);
}